// Round 13
// baseline (166.914 us; speedup 1.0000x reference)
//
#include <hip/hip_runtime.h>
#include <math.h>

#define BATCH 4
#define SEQ   4096
#define EMB   1024
#define HD    128
#define MROWS (BATCH*SEQ)
#define SCALE  0.08838834764831844f   // 1/sqrt(128)
#define SCALEQ 0.12751742f            // (1/sqrt(128)) * log2(e)  -> exp2-domain scores
#define CHUNK 10                      // kv-tiles (of 64) per split-KV job
#define NJOBS 119                     // jobs per batch at BQ=128, CHUNK=10 (minimal-makespan)
#define MAXC  7                       // max chunks per q-tile = ceil(64/10)

typedef __attribute__((ext_vector_type(8))) short bf16x8;   // MFMA A/B frag (4 VGPR)
typedef __attribute__((ext_vector_type(4))) short short4v;  // 8B LDS store
typedef __attribute__((ext_vector_type(4))) float f32x4;    // MFMA C/D frag
typedef __attribute__((ext_vector_type(4))) int   i32x4;    // 16B copy
typedef __attribute__((ext_vector_type(2))) int   i32x2;    // 8B copy

static __device__ __forceinline__ unsigned short f2bf(float f) {
    unsigned int u = __float_as_uint(f);
    u += 0x7fff + ((u >> 16) & 1);       // RNE
    return (unsigned short)(u >> 16);
}
static __device__ __forceinline__ float bf2f(unsigned short s) {
    return __uint_as_float((unsigned int)s << 16);
}
static __device__ __forceinline__ short4v pack4(float4 a) {
    short4v p;
    p[0] = (short)f2bf(a.x); p[1] = (short)f2bf(a.y);
    p[2] = (short)f2bf(a.z); p[3] = (short)f2bf(a.w);
    return p;
}
// HW packed f32->bf16 RNE
static __device__ __forceinline__ int cvtpk(float lo, float hi) {
    int r;
    asm("v_cvt_pk_bf16_f32 %0, %1, %2" : "=v"(r) : "v"(lo), "v"(hi));
    return r;
}
// async global->LDS, 16B/lane: dest = wave-uniform base + lane*16 (linear)
static __device__ __forceinline__ void gload_lds16(const unsigned short* g, unsigned short* l) {
    __builtin_amdgcn_global_load_lds(
        (const __attribute__((address_space(1))) void*)g,
        (__attribute__((address_space(3))) void*)l, 16, 0, 0);
}

// ---------------- W transpose + bf16 -> FRAGMENT-CONTIGUOUS layout ----------------
__global__ __launch_bounds__(256) void wtrans_kernel(
    const float* __restrict__ Wq, const float* __restrict__ Wk,
    const float* __restrict__ Wv, unsigned short* __restrict__ Wt)
{
    __shared__ __align__(16) unsigned short Xs[16 * 132];
    const int w  = blockIdx.y;
    const float* W = (w == 0) ? Wq : (w == 1) ? Wk : Wv;
    const float sc = (w == 0) ? SCALEQ : 1.0f;   // exp2-domain: scores carry log2(e)
    const int bx = blockIdx.x;
    const int k0 = bx * 16;
    const int t  = threadIdx.x;

#pragma unroll
    for (int i = 0; i < 2; ++i) {
        int gg = i * 256 + t;                 // 0..511
        int row = gg >> 5, c4 = gg & 31;
        float4 a = *(const float4*)&W[(size_t)(k0 + row) * HD + c4 * 4];
        short4v p;
        p[0] = (short)f2bf(a.x * sc); p[1] = (short)f2bf(a.y * sc);
        p[2] = (short)f2bf(a.z * sc); p[3] = (short)f2bf(a.w * sc);
        *(short4v*)&Xs[row * 132 + c4 * 4] = p;
    }
    __syncthreads();
    const int n = t >> 1, g = t & 1;
    i32x4 o;
#pragma unroll
    for (int e = 0; e < 4; ++e) {
        unsigned int lo = Xs[(g * 8 + e * 2    ) * 132 + n];
        unsigned int hi = Xs[(g * 8 + e * 2 + 1) * 132 + n];
        o[e] = (int)(lo | (hi << 16));
    }
    const int ntg  = w * 8 + (n >> 4);
    const int kc   = bx >> 1;
    const int quad = (bx * 2 + g) & 3;
    const int lane = quad * 16 + (n & 15);
    *(i32x4*)&Wt[(((size_t)ntg * 32 + kc) * 64 + lane) * 8] = o;
}

// ---------------- Fused QKV: 32-K phases, 57KB LDS -> 2 blocks/CU ----------------
// Round-13 restructure: the old 96KB W dbuf forced 1 block/CU, so the 32 barriers
// per block had ZERO cross-block overlap (m233 stall regime). Halving the phase
// K-step (64->32) halves the W dbuf to 48KB; x pair-buffered (9KB) -> 57KB total,
// grid 512 x M=32, 2 blocks/CU co-resident: a second block computes through every
// barrier stall. W L2 traffic doubles (201->402MB ~ 11.5us at L2 BW) - well under
// the 40us being attacked. Static A/B sub-phases keep counted-vmcnt wave-uniform:
//  sub-A: 3 Wglds->buf1 | issue x-pair load | compute(buf0, x par0) | vmcnt(1)
//  sub-B: 3 Wglds->buf0 | write-late x ds_write | compute(buf1, x par1) | vmcnt(0)
__global__ __launch_bounds__(512, 2) void qkv_kernel(
    const float* __restrict__ x, const unsigned short* __restrict__ Wt,
    unsigned short* __restrict__ qb, unsigned short* __restrict__ kb,
    unsigned short* __restrict__ vtb)
{
    __shared__ __align__(1024) unsigned short lds[29184];  // 57KB
    unsigned short* Ws  = lds;           // [2][24][512] shorts (buf, ntg, 1KB frag)
    unsigned short* xsA = lds + 24576;   // x pair buf 0: [32][72]
    unsigned short* xsB = lds + 26880;   // x pair buf 1

    const int t    = threadIdx.x;
    const int lane = t & 63, ng = t >> 6;
    const int quad = lane >> 4, l16 = lane & 15;
    const int m0   = blockIdx.x * 32;
    const int nt0  = ng * 3;

    f32x4 acc[2][3];
#pragma unroll
    for (int i = 0; i < 2; ++i)
#pragma unroll
        for (int j = 0; j < 3; ++j) acc[i][j] = (f32x4){0.f, 0.f, 0.f, 0.f};

    // x staging: pair = 32 rows x 64 cols; 512 thr x 1 float4
    const int xrow = t >> 4, xseg = (t & 15) * 4;
    const float* xbase = x + (size_t)(m0 + xrow) * EMB + xseg;
    const unsigned short* Wg = Wt + (size_t)lane * 8;

    float4 xr;
    // prologue: x pair0 -> xsA; W kc0 -> Wbuf0
    {
        float4 a = *(const float4*)&xbase[0];
        *(short4v*)&xsA[xrow * 72 + xseg] = pack4(a);
#pragma unroll
        for (int jt = 0; jt < 3; ++jt)
            gload_lds16(Wg + (size_t)((nt0 + jt) * 32) * 512,
                        Ws + (size_t)(nt0 + jt) * 512);
    }
    asm volatile("s_waitcnt vmcnt(0)" ::: "memory");
    asm volatile("s_waitcnt lgkmcnt(0)" ::: "memory");
    __builtin_amdgcn_s_barrier();

    for (int it = 0; it < 16; ++it) {
        unsigned short* xc = (it & 1) ? xsB : xsA;   // pair it
        unsigned short* xn = (it & 1) ? xsA : xsB;   // pair it+1
        // ======== sub-A: phase 2it (K cols it*64..+32), reads Wbuf0 ========
        {
            const int kcn = 2 * it + 1;              // stage next into Wbuf1
#pragma unroll
            for (int jt = 0; jt < 3; ++jt)
                gload_lds16(Wg + ((size_t)((nt0 + jt) * 32) + kcn) * 512,
                            Ws + ((size_t)24 + nt0 + jt) * 512);
            const int pc = (it + 1 < 16) ? it + 1 : 15;   // issue x pair it+1 (clamped)
            xr = *(const float4*)&xbase[pc * 64];
            bf16x8 aA[2], aB[3];
#pragma unroll
            for (int jt = 0; jt < 3; ++jt)
                aB[jt] = *(const bf16x8*)&Ws[(size_t)(nt0 + jt) * 512 + lane * 8];
#pragma unroll
            for (int mt = 0; mt < 2; ++mt)
                aA[mt] = *(const bf16x8*)&xc[(mt * 16 + l16) * 72 + quad * 8];
            __builtin_amdgcn_s_setprio(1);
#pragma unroll
            for (int mt = 0; mt < 2; ++mt)
#pragma unroll
                for (int jt = 0; jt < 3; ++jt)
                    acc[mt][jt] = __builtin_amdgcn_mfma_f32_16x16x32_bf16(
                        aA[mt], aB[jt], acc[mt][jt], 0, 0, 0);
            __builtin_amdgcn_s_setprio(0);
            asm volatile("s_waitcnt vmcnt(1)" ::: "memory");   // 3 W done; xr in flight
            asm volatile("s_waitcnt lgkmcnt(0)" ::: "memory");
            __builtin_amdgcn_s_barrier();
        }
        // ======== sub-B: phase 2it+1 (K cols it*64+32..+64), reads Wbuf1 ========
        {
            const int kcn = (2 * it + 2 < 32) ? 2 * it + 2 : 31;  // stage next into Wbuf0
#pragma unroll
            for (int jt = 0; jt < 3; ++jt)
                gload_lds16(Wg + ((size_t)((nt0 + jt) * 32) + kcn) * 512,
                            Ws + (size_t)(nt0 + jt) * 512);
            // write-late: x pair it+1 (loaded in sub-A) -> other buffer
            *(short4v*)&xn[xrow * 72 + xseg] = pack4(xr);   // waits xr only; W in flight
            bf16x8 aA[2], aB[3];
#pragma unroll
            for (int jt = 0; jt < 3; ++jt)
                aB[jt] = *(const bf16x8*)&Ws[((size_t)24 + nt0 + jt) * 512 + lane * 8];
#pragma unroll
            for (int mt = 0; mt < 2; ++mt)
                aA[mt] = *(const bf16x8*)&xc[(mt * 16 + l16) * 72 + 32 + quad * 8];
            __builtin_amdgcn_s_setprio(1);
#pragma unroll
            for (int mt = 0; mt < 2; ++mt)
#pragma unroll
                for (int jt = 0; jt < 3; ++jt)
                    acc[mt][jt] = __builtin_amdgcn_mfma_f32_16x16x32_bf16(
                        aA[mt], aB[jt], acc[mt][jt], 0, 0, 0);
            __builtin_amdgcn_s_setprio(0);
            asm volatile("s_waitcnt vmcnt(0)" ::: "memory");   // drain W (xr already waited)
            asm volatile("s_waitcnt lgkmcnt(0)" ::: "memory");
            __builtin_amdgcn_s_barrier();
        }
    }

    __syncthreads();
    // ---- epilogue (M=32, R0-verified): scatter to LDS, coalesced copy out ----
    unsigned short* Cq = lds;                 // [32][136]
    unsigned short* Ck = lds + 32 * 136;      // [32][136]
    unsigned short* Cv = lds + 2 * 32 * 136;  // [128][40] transposed
#pragma unroll
    for (int mt = 0; mt < 2; ++mt)
#pragma unroll
        for (int jt = 0; jt < 3; ++jt) {
            int nt = ng * 3 + jt;
            int wm = nt >> 3, nl = nt & 7;
            if (wm < 2) {
                unsigned short* C = (wm == 0) ? Cq : Ck;
#pragma unroll
                for (int rr = 0; rr < 4; ++rr)
                    C[(mt * 16 + quad * 4 + rr) * 136 + nl * 16 + l16] =
                        f2bf(acc[mt][jt][rr]);
            } else {
                i32x2 p;
                p[0] = cvtpk(acc[mt][jt][0], acc[mt][jt][1]);
                p[1] = cvtpk(acc[mt][jt][2], acc[mt][jt][3]);
                *(i32x2*)&Cv[(nl * 16 + l16) * 40 + mt * 16 + quad * 4] = p;
            }
        }
    __syncthreads();
    {   // q, k: 32 x 128 each -> 512 i32x4, one per thread
        int row = t >> 4, seg = t & 15;
        *(i32x4*)&qb[((size_t)(m0 + row)) * HD + seg * 8] = *(const i32x4*)&Cq[row * 136 + seg * 8];
        *(i32x4*)&kb[((size_t)(m0 + row)) * HD + seg * 8] = *(const i32x4*)&Ck[row * 136 + seg * 8];
    }
    {   // v^T: 128 x 32 -> 512 i32x4, one per thread
        const int b = m0 >> 12, s0 = m0 & 4095;
        int h = t >> 2, seg = t & 3;
        *(i32x4*)&vtb[(size_t)b * (HD * SEQ) + (size_t)h * SEQ + s0 + seg * 8] =
            *(const i32x4*)&Cv[h * 40 + seg * 8];
    }
}

// ---------------- Flash attention: 4 waves x 32 q-rows (round-12 best — unchanged) ----------------
#define PADK 136
#define PADV 72
#define PADP 72
#define DEFER_THR 8.0f   // log2 domain: P bounded by 2^8=256, safe in bf16/f32

__global__ __launch_bounds__(256, 2) void flash_kernel(
    const unsigned short* __restrict__ qb, const unsigned short* __restrict__ kb,
    const unsigned short* __restrict__ vtb, unsigned short* __restrict__ Opart,
    float* __restrict__ mbuf, float* __restrict__ lbuf)
{
    __shared__ __align__(16) unsigned short Ks[64 * PADK];    // 17.4 KB
    __shared__ __align__(16) unsigned short Vt[128 * PADV];   // 18.4 KB
    __shared__ __align__(16) unsigned short Pt[128 * PADP];   // 18.4 KB

    const int bx   = blockIdx.x;
    const int slot = bx & 7, pp = bx >> 3;
    const int b    = slot >> 1;
    const int jj   = pp * 2 + (slot & 1);
    if (jj >= NJOBS) return;

    const int t    = threadIdx.x;
    const int lane = t & 63, w = t >> 6;     // 4 waves, 32 q-rows each
    const int quad = lane >> 4, l16 = lane & 15;

    int qi = 0, s = 0;
    for (qi = 0; qi < 32; ++qi) {
        int cnt = (qi + 5) / 5;
        if (jj < s + cnt) break;
        s += cnt;
    }
    const int c     = jj - s;
    const int qrow0 = qi * 128 + w * 32 + l16;        // sub 0
    const int qrow1 = qrow0 + 16;                     // sub 1
    const int jmax  = 2 * qi + 2;
    const int jbeg  = c * CHUNK;
    const int jend  = min(jbeg + CHUNK, jmax);
    const int wtop  = qi * 128 + w * 32;              // wave's lowest q-row (32-row span)

    bf16x8 qf0[4], qf1[4];
    {
        const unsigned short* qp0 = qb + ((size_t)b * SEQ + qrow0) * HD;
        const unsigned short* qp1 = qb + ((size_t)b * SEQ + qrow1) * HD;
#pragma unroll
        for (int ks = 0; ks < 4; ++ks) {
            qf0[ks] = *(const bf16x8*)&qp0[ks * 32 + quad * 8];
            qf1[ks] = *(const bf16x8*)&qp1[ks * 32 + quad * 8];
        }
    }

    f32x4 O0[8], O1[8];
#pragma unroll
    for (int i = 0; i < 8; ++i) {
        O0[i] = (f32x4){0.f, 0.f, 0.f, 0.f};
        O1[i] = (f32x4){0.f, 0.f, 0.f, 0.f};
    }
    float m0r = -1e30f, l0r = 0.f, m1r = -1e30f, l1r = 0.f;

    const unsigned short* kbb  = kb  + (size_t)b * SEQ * HD;
    const unsigned short* vtbb = vtb + (size_t)b * HD * SEQ;

    // staging: 256 threads cover 1024 16B chunks each of K and V^T
    i32x4 kr[4], vr[4];
#pragma unroll
    for (int i = 0; i < 4; ++i) {
        int gg = i * 256 + t;
        kr[i] = *(const i32x4*)&kbb[(size_t)jbeg * 64 * HD + (size_t)gg * 8];
        vr[i] = *(const i32x4*)&vtbb[(size_t)(gg >> 3) * SEQ + jbeg * 64 + (gg & 7) * 8];
    }

    for (int j0 = jbeg; j0 < jend; ++j0) {
        __syncthreads();   // prior iteration's reads of Ks/Vt complete (WAR)
#pragma unroll
        for (int i = 0; i < 4; ++i) {
            int gg = i * 256 + t;
            *(i32x4*)&Ks[(gg >> 4) * PADK + (gg & 15) * 8] = kr[i];
            *(i32x4*)&Vt[(gg >> 3) * PADV + (gg & 7) * 8] = vr[i];
        }
        __syncthreads();

        // issue next tile's loads NOW — latency hides under this tile's compute
        if (j0 + 1 < jend) {
            const int j1 = j0 + 1;
#pragma unroll
            for (int i = 0; i < 4; ++i) {
                int gg = i * 256 + t;
                kr[i] = *(const i32x4*)&kbb[(size_t)j1 * 64 * HD + (size_t)gg * 8];
                vr[i] = *(const i32x4*)&vtbb[(size_t)(gg >> 3) * SEQ + j1 * 64 + (gg & 7) * 8];
            }
        }

        // fully-masked tile for this wave's 32 rows? -> skip compute
        if (j0 * 64 > wtop + 31) continue;

        // ---- S^T = K . Q^T : each kf read feeds BOTH q-subtiles ----
        f32x4 st0[4], st1[4];
#pragma unroll
        for (int mt = 0; mt < 4; ++mt) {
            st0[mt] = (f32x4){0.f, 0.f, 0.f, 0.f};
            st1[mt] = (f32x4){0.f, 0.f, 0.f, 0.f};
        }
        __builtin_amdgcn_s_setprio(1);
#pragma unroll
        for (int mt = 0; mt < 4; ++mt)
#pragma unroll
            for (int ks = 0; ks < 4; ++ks) {
                bf16x8 kf = *(const bf16x8*)&Ks[(mt * 16 + l16) * PADK + ks * 32 + quad * 8];
                st0[mt] = __builtin_amdgcn_mfma_f32_16x16x32_bf16(kf, qf0[ks], st0[mt], 0, 0, 0);
                st1[mt] = __builtin_amdgcn_mfma_f32_16x16x32_bf16(kf, qf1[ks], st1[mt], 0, 0, 0);
            }
        __builtin_amdgcn_s_setprio(0);

        // ---- causal mask (both subtiles) ----
        if (j0 * 64 + 63 > wtop) {
#pragma unroll
            for (int mt = 0; mt < 4; ++mt)
#pragma unroll
                for (int rr = 0; rr < 4; ++rr) {
                    int kv = j0 * 64 + mt * 16 + quad * 4 + rr;
                    if (kv > qrow0) st0[mt][rr] = -1e30f;
                    if (kv > qrow1) st1[mt][rr] = -1e30f;
                }
        }

        // ---- online softmax, exp2 domain, per subtile (lane owns one q-row each) ----
        {
            float mx = -1e30f;
#pragma unroll
            for (int mt = 0; mt < 4; ++mt)
#pragma unroll
                for (int rr = 0; rr < 4; ++rr) mx = fmaxf(mx, st0[mt][rr]);
            mx = fmaxf(mx, __shfl_xor(mx, 16));
            mx = fmaxf(mx, __shfl_xor(mx, 32));
            if (!__all(mx <= m0r + DEFER_THR)) {
                const float m_new = fmaxf(m0r, mx);
                const float alpha = exp2f(m0r - m_new);
                l0r *= alpha;
#pragma unroll
                for (int i = 0; i < 8; ++i) {
                    O0[i][0] *= alpha; O0[i][1] *= alpha; O0[i][2] *= alpha; O0[i][3] *= alpha;
                }
                m0r = m_new;
            }
            float psum = 0.f;
#pragma unroll
            for (int mt = 0; mt < 4; ++mt)
#pragma unroll
                for (int rr = 0; rr < 4; ++rr) {
                    float p = exp2f(st0[mt][rr] - m0r);
                    st0[mt][rr] = p;
                    psum += p;
                }
            psum += __shfl_xor(psum, 16);
            psum += __shfl_xor(psum, 32);
            l0r += psum;
            // pack sub0 P to LDS immediately so st0 dies here (register pressure)
#pragma unroll
            for (int mt = 0; mt < 4; ++mt) {
                i32x2 p;
                p[0] = cvtpk(st0[mt][0], st0[mt][1]);
                p[1] = cvtpk(st0[mt][2], st0[mt][3]);
                *(i32x2*)&Pt[(w * 32 + l16) * PADP + mt * 16 + quad * 4] = p;
            }
        }
        {
            float mx = -1e30f;
#pragma unroll
            for (int mt = 0; mt < 4; ++mt)
#pragma unroll
                for (int rr = 0; rr < 4; ++rr) mx = fmaxf(mx, st1[mt][rr]);
            mx = fmaxf(mx, __shfl_xor(mx, 16));
            mx = fmaxf(mx, __shfl_xor(mx, 32));
            if (!__all(mx <= m1r + DEFER_THR)) {
                const float m_new = fmaxf(m1r, mx);
                const float alpha = exp2f(m1r - m_new);
                l1r *= alpha;
#pragma unroll
                for (int i = 0; i < 8; ++i) {
                    O1[i][0] *= alpha; O1[i][1] *= alpha; O1[i][2] *= alpha; O1[i][3] *= alpha;
                }
                m1r = m_new;
            }
            float psum = 0.f;
#pragma unroll
            for (int mt = 0; mt < 4; ++mt)
#pragma unroll
                for (int rr = 0; rr < 4; ++rr) {
                    float p = exp2f(st1[mt][rr] - m1r);
                    st1[mt][rr] = p;
                    psum += p;
                }
            psum += __shfl_xor(psum, 16);
            psum += __shfl_xor(psum, 32);
            l1r += psum;
#pragma unroll
            for (int mt = 0; mt < 4; ++mt) {
                i32x2 p;
                p[0] = cvtpk(st1[mt][0], st1[mt][1]);
                p[1] = cvtpk(st1[mt][2], st1[mt][3]);
                *(i32x2*)&Pt[(w * 32 + 16 + l16) * PADP + mt * 16 + quad * 4] = p;
            }
        }

        // ---- O^T += V^T . P^T : each vf read feeds BOTH q-subtiles ----
        bf16x8 pf00 = *(const bf16x8*)&Pt[(w * 32 + l16) * PADP + quad * 8];
        bf16x8 pf01 = *(const bf16x8*)&Pt[(w * 32 + l16) * PADP + 32 + quad * 8];
        bf16x8 pf10 = *(const bf16x8*)&Pt[(w * 32 + 16 + l16) * PADP + quad * 8];
        bf16x8 pf11 = *(const bf16x8*)&Pt[(w * 32 + 16 + l16) * PADP + 32 + quad * 8];
        __builtin_amdgcn_s_setprio(1);
#pragma unroll
        for (int mt = 0; mt < 8; ++mt) {
            bf16x8 vf0 = *(const bf16x8*)&Vt[(mt * 16 + l16) * PADV + quad * 8];
            bf16x8 vf1 = *(const bf16x8*)&Vt[(mt * 16 + l16) * PADV + 32 + quad * 8];
            O0[mt] = __builtin_amdgcn_mfma_f32_16x16x32_bf16(vf0, pf00, O0[mt], 0, 0, 0);
            O0[mt] = __builtin_amdgcn_mfma_f32_16x16x32_bf16(vf1, pf01, O0[mt], 0, 0, 0);
            O1[mt] = __builtin_amdgcn_mfma_f32_16x16x32_bf16(vf0, pf10, O1[mt], 0, 0, 0);
            O1[mt] = __builtin_amdgcn_mfma_f32_16x16x32_bf16(vf1, pf11, O1[mt], 0, 0, 0);
        }
        __builtin_amdgcn_s_setprio(0);
    }

    // ---- partial epilogue: unnormalized O (bf16, cvt_pk) + m,l (log2 domain) ----
    const size_t jobbase = (size_t)b * NJOBS + jj;
    {
        const int r = w * 32 + l16;
        unsigned short* po = Opart + jobbase * (128 * 128) + (size_t)r * 128;
#pragma unroll
        for (int mt = 0; mt < 8; ++mt) {
            i32x2 p;
            p[0] = cvtpk(O0[mt][0], O0[mt][1]);
            p[1] = cvtpk(O0[mt][2], O0[mt][3]);
            *(i32x2*)&po[mt * 16 + quad * 4] = p;
        }
        if (quad == 0) {
            mbuf[jobbase * 128 + r] = m0r;
            lbuf[jobbase * 128 + r] = l0r;
        }
    }
    {
        const int r = w * 32 + 16 + l16;
        unsigned short* po = Opart + jobbase * (128 * 128) + (size_t)r * 128;
#pragma unroll
        for (int mt = 0; mt < 8; ++mt) {
            i32x2 p;
            p[0] = cvtpk(O1[mt][0], O1[mt][1]);
            p[1] = cvtpk(O1[mt][2], O1[mt][3]);
            *(i32x2*)&po[mt * 16 + quad * 4] = p;
        }
        if (quad == 0) {
            mbuf[jobbase * 128 + r] = m1r;
            lbuf[jobbase * 128 + r] = l1r;
        }
    }
}

// ---------------- Combine partials (round-13: 4-way z-split, 2x more parallel) ----------------
// grid (32, 4, 4) x 512 thr: block z covers 32 rows; thread -> row = bz*32 + (t>>4),
// 8 head cols at (t&15)*8. Per chunk: one 16B load. Halves per-thread serial work vs R8.
__global__ __launch_bounds__(512) void combine_kernel(
    const unsigned short* __restrict__ Opart, const float* __restrict__ mbuf,
    const float* __restrict__ lbuf, float* __restrict__ out)
{
    const int qi = blockIdx.x, b = blockIdx.y;
    const int nc = (qi + 5) / 5;
    int j0 = 0;
    for (int q = 0; q < qi; ++q) j0 += (q + 5) / 5;
    const int t = threadIdx.x;
    const int row = blockIdx.z * 32 + (t >> 4);
    const int cg  = (t & 15) * 8;

    float mv[MAXC], lv[MAXC];
    float M = -1e30f;
#pragma unroll
    for (int c2 = 0; c2 < MAXC; ++c2) {
        if (c2 < nc) {
            const size_t jb = (size_t)b * NJOBS + j0 + c2;
            mv[c2] = mbuf[jb * 128 + row];
            lv[c2] = lbuf[jb * 128 + row];
            M = fmaxf(M, mv[c2]);
        } else { mv[c2] = -1e30f; lv[c2] = 0.f; }
    }
    float L = 0.f;
#pragma unroll
    for (int c2 = 0; c2 < MAXC; ++c2)
        if (c2 < nc) L += exp2f(mv[c2] - M) * lv[c2];
    const float Linv = 1.0f / L;

    float acc[8];
#pragma unroll
    for (int i = 0; i < 8; ++i) acc[i] = 0.f;
#pragma unroll
    for (int c2 = 0; c2 < MAXC; ++c2) {
        if (c2 < nc) {
            const float wgt = exp2f(mv[c2] - M) * Linv;
            const unsigned short* po = Opart + ((size_t)b * NJOBS + j0 + c2) * (128 * 128) +
                                       (size_t)row * 128 + cg;
            i32x4 d = *(const i32x4*)&po[0];
#pragma unroll
            for (int e = 0; e < 4; ++e) {
                unsigned int u = (unsigned int)d[e];
                acc[e * 2]     = fmaf(wgt, bf2f((unsigned short)(u & 0xffff)), acc[e * 2]);
                acc[e * 2 + 1] = fmaf(wgt, bf2f((unsigned short)(u >> 16)),   acc[e * 2 + 1]);
            }
        }
    }
    float* op = out + ((size_t)b * SEQ + qi * 128 + row) * HD + cg;
#pragma unroll
    for (int i = 0; i < 2; ++i) {
        float4 res;
        res.x = acc[i * 4]; res.y = acc[i * 4 + 1];
        res.z = acc[i * 4 + 2]; res.w = acc[i * 4 + 3];
        *(float4*)&op[i * 4] = res;
    }
}

extern "C" void kernel_launch(void* const* d_in, const int* in_sizes, int n_in,
                              void* d_out, int out_size, void* d_ws, size_t ws_size,
                              hipStream_t stream) {
    const float* x  = (const float*)d_in[0];
    const float* Wq = (const float*)d_in[1];
    const float* Wk = (const float*)d_in[2];
    const float* Wv = (const float*)d_in[3];

    unsigned short* qb    = (unsigned short*)d_ws;          // [16384][128] bf16
    unsigned short* kb    = qb  + (size_t)MROWS * HD;       // [16384][128] bf16
    unsigned short* vtb   = kb  + (size_t)MROWS * HD;       // [4][128][4096] bf16
    unsigned short* Wt    = vtb + (size_t)MROWS * HD;       // [24][32][64][8] bf16 frag-order
    unsigned short* Opart = Wt  + (size_t)3 * HD * EMB;     // [4][119][128][128] bf16
    float* mbuf = (float*)(Opart + (size_t)BATCH * NJOBS * 128 * 128);
    float* lbuf = mbuf + (size_t)BATCH * NJOBS * 128;
    float* out = (float*)d_out;

    wtrans_kernel <<<dim3(64, 3),    dim3(256), 0, stream>>>(Wq, Wk, Wv, Wt);
    qkv_kernel    <<<dim3(512),      dim3(512), 0, stream>>>(x, Wt, qb, kb, vtb);
    flash_kernel  <<<dim3(480),      dim3(256), 0, stream>>>(qb, kb, vtb, Opart, mbuf, lbuf);
    combine_kernel<<<dim3(32, 4, 4), dim3(512), 0, stream>>>(Opart, mbuf, lbuf, out);
}

// Round 14
// 164.643 us; speedup vs baseline: 1.0138x; 1.0138x over previous
//
#include <hip/hip_runtime.h>
#include <math.h>

#define BATCH 4
#define SEQ   4096
#define EMB   1024
#define HD    128
#define MROWS (BATCH*SEQ)
#define SCALE  0.08838834764831844f   // 1/sqrt(128)
#define SCALEQ 0.12751742f            // (1/sqrt(128)) * log2(e)  -> exp2-domain scores
#define CHUNK 10                      // kv-tiles (of 64) per split-KV job
#define NJOBS 119                     // jobs per batch at BQ=128, CHUNK=10 (minimal-makespan)
#define MAXC  7                       // max chunks per q-tile = ceil(64/10)

typedef __attribute__((ext_vector_type(8))) short bf16x8;   // MFMA A/B frag (4 VGPR)
typedef __attribute__((ext_vector_type(4))) short short4v;  // 8B LDS store
typedef __attribute__((ext_vector_type(4))) float f32x4;    // MFMA C/D frag
typedef __attribute__((ext_vector_type(4))) int   i32x4;    // 16B copy
typedef __attribute__((ext_vector_type(2))) int   i32x2;    // 8B copy

static __device__ __forceinline__ unsigned short f2bf(float f) {
    unsigned int u = __float_as_uint(f);
    u += 0x7fff + ((u >> 16) & 1);       // RNE
    return (unsigned short)(u >> 16);
}
static __device__ __forceinline__ float bf2f(unsigned short s) {
    return __uint_as_float((unsigned int)s << 16);
}
static __device__ __forceinline__ short4v pack4(float4 a) {
    short4v p;
    p[0] = (short)f2bf(a.x); p[1] = (short)f2bf(a.y);
    p[2] = (short)f2bf(a.z); p[3] = (short)f2bf(a.w);
    return p;
}
// HW packed f32->bf16 RNE
static __device__ __forceinline__ int cvtpk(float lo, float hi) {
    int r;
    asm("v_cvt_pk_bf16_f32 %0, %1, %2" : "=v"(r) : "v"(lo), "v"(hi));
    return r;
}
// async global->LDS, 16B/lane: dest = wave-uniform base + lane*16 (linear)
static __device__ __forceinline__ void gload_lds16(const unsigned short* g, unsigned short* l) {
    __builtin_amdgcn_global_load_lds(
        (const __attribute__((address_space(1))) void*)g,
        (__attribute__((address_space(3))) void*)l, 16, 0, 0);
}

// ---------------- W transpose + bf16 -> FRAGMENT-CONTIGUOUS layout ----------------
__global__ __launch_bounds__(256) void wtrans_kernel(
    const float* __restrict__ Wq, const float* __restrict__ Wk,
    const float* __restrict__ Wv, unsigned short* __restrict__ Wt)
{
    __shared__ __align__(16) unsigned short Xs[16 * 132];
    const int w  = blockIdx.y;
    const float* W = (w == 0) ? Wq : (w == 1) ? Wk : Wv;
    const float sc = (w == 0) ? SCALEQ : 1.0f;   // exp2-domain: scores carry log2(e)
    const int bx = blockIdx.x;
    const int k0 = bx * 16;
    const int t  = threadIdx.x;

#pragma unroll
    for (int i = 0; i < 2; ++i) {
        int gg = i * 256 + t;                 // 0..511
        int row = gg >> 5, c4 = gg & 31;
        float4 a = *(const float4*)&W[(size_t)(k0 + row) * HD + c4 * 4];
        short4v p;
        p[0] = (short)f2bf(a.x * sc); p[1] = (short)f2bf(a.y * sc);
        p[2] = (short)f2bf(a.z * sc); p[3] = (short)f2bf(a.w * sc);
        *(short4v*)&Xs[row * 132 + c4 * 4] = p;
    }
    __syncthreads();
    const int n = t >> 1, g = t & 1;
    i32x4 o;
#pragma unroll
    for (int e = 0; e < 4; ++e) {
        unsigned int lo = Xs[(g * 8 + e * 2    ) * 132 + n];
        unsigned int hi = Xs[(g * 8 + e * 2 + 1) * 132 + n];
        o[e] = (int)(lo | (hi << 16));
    }
    const int ntg  = w * 8 + (n >> 4);
    const int kc   = bx >> 1;
    const int quad = (bx * 2 + g) & 3;
    const int lane = quad * 16 + (n & 15);
    *(i32x4*)&Wt[(((size_t)ntg * 32 + kc) * 64 + lane) * 8] = o;
}

// ---------------- Fused QKV (round-5/8/12 envelope minimum — restored) ----------------
// Seven staging schemes measured (39-81us); this is the minimum. The 96KB W dbuf ->
// 1 block/CU is structural; R13's 2-block/CU variant (32-K phases) was +2.5us.
__global__ __launch_bounds__(512, 2) void qkv_kernel(
    const float* __restrict__ x, const unsigned short* __restrict__ Wt,
    unsigned short* __restrict__ qb, unsigned short* __restrict__ kb,
    unsigned short* __restrict__ vtb)
{
    __shared__ __align__(1024) unsigned short lds[58368];  // W dbuf 96KB + x dbuf 18.4KB
    unsigned short* Ws  = lds;
    unsigned short* xsA = lds + 49152;
    unsigned short* xsB = lds + 53760;

    const int t    = threadIdx.x;
    const int lane = t & 63, ng = t >> 6;
    const int quad = lane >> 4, l16 = lane & 15;
    const int m0   = blockIdx.x * 64;

    f32x4 acc[4][3];
#pragma unroll
    for (int i = 0; i < 4; ++i)
#pragma unroll
        for (int j = 0; j < 3; ++j) acc[i][j] = (f32x4){0.f, 0.f, 0.f, 0.f};

    const int xr0 = t >> 4,         xc0 = (t & 15) * 4;
    const int xr1 = (t + 512) >> 4, xc1 = ((t + 512) & 15) * 4;
    const float* xb0 = x + (size_t)(m0 + xr0) * EMB + xc0;
    const float* xb1 = x + (size_t)(m0 + xr1) * EMB + xc1;

    const unsigned short* Wg = Wt + (size_t)lane * 8;
    float4 xra, xrb;

    {
        float4 a = *(const float4*)&xb0[0];
        float4 b = *(const float4*)&xb1[0];
        *(short4v*)&xsA[xr0 * 72 + xc0] = pack4(a);
        *(short4v*)&xsA[xr1 * 72 + xc1] = pack4(b);
#pragma unroll
        for (int jt = 0; jt < 3; ++jt)
#pragma unroll
            for (int kcl = 0; kcl < 2; ++kcl) {
                int ntg = ng * 3 + jt;
                gload_lds16(Wg + ((size_t)ntg * 32 + kcl) * 512,
                            Ws + ((size_t)ntg * 2 + kcl) * 512);
            }
        xra = *(const float4*)&xb0[64];
        xrb = *(const float4*)&xb1[64];
    }
    asm volatile("s_waitcnt vmcnt(2)" ::: "memory");
    asm volatile("s_waitcnt lgkmcnt(0)" ::: "memory");
    __builtin_amdgcn_s_barrier();

    for (int ph = 0; ph < 16; ++ph) {
        const int cb = ph & 1, nb = cb ^ 1;
        unsigned short* xc = cb ? xsB : xsA;
        unsigned short* xn = cb ? xsA : xsB;
        const int kcn = (ph < 15 ? ph + 1 : 15) * 2;

#pragma unroll
        for (int jt = 0; jt < 3; ++jt)
#pragma unroll
            for (int kcl = 0; kcl < 2; ++kcl) {
                int ntg = ng * 3 + jt;
                gload_lds16(Wg + ((size_t)ntg * 32 + kcn + kcl) * 512,
                            Ws + ((size_t)(nb * 48) + ntg * 2 + kcl) * 512);
            }
        *(short4v*)&xn[xr0 * 72 + xc0] = pack4(xra);
        *(short4v*)&xn[xr1 * 72 + xc1] = pack4(xrb);
        {
            const int xcol = (ph + 2 < 16) ? (ph + 2) * 64 : 960;
            xra = *(const float4*)&xb0[xcol];
            xrb = *(const float4*)&xb1[xcol];
        }
        {
            bf16x8 aA[2][4], aB[2][3];
#pragma unroll
            for (int ks = 0; ks < 2; ++ks)
#pragma unroll
                for (int jt = 0; jt < 3; ++jt)
                    aB[ks][jt] = *(const bf16x8*)&Ws[((size_t)(cb * 48) + (ng * 3 + jt) * 2 + ks) * 512 + lane * 8];
#pragma unroll
            for (int ks = 0; ks < 2; ++ks)
#pragma unroll
                for (int mt = 0; mt < 4; ++mt)
                    aA[ks][mt] = *(const bf16x8*)&xc[(mt * 16 + l16) * 72 + ks * 32 + quad * 8];
            __builtin_amdgcn_s_setprio(1);
#pragma unroll
            for (int ks = 0; ks < 2; ++ks)
#pragma unroll
                for (int mt = 0; mt < 4; ++mt)
#pragma unroll
                    for (int jt = 0; jt < 3; ++jt)
                        acc[mt][jt] = __builtin_amdgcn_mfma_f32_16x16x32_bf16(
                            aA[ks][mt], aB[ks][jt], acc[mt][jt], 0, 0, 0);
            __builtin_amdgcn_s_setprio(0);
        }
        asm volatile("s_waitcnt vmcnt(2)" ::: "memory");
        asm volatile("s_waitcnt lgkmcnt(0)" ::: "memory");
        __builtin_amdgcn_s_barrier();
    }

    // ---- epilogue ----
    unsigned short* Cq = lds;                 // [64][136]
    unsigned short* Ck = lds + 64 * 136;      // [64][136]
    unsigned short* Cv = lds + 2 * 64 * 136;  // [128][72] transposed
#pragma unroll
    for (int mt = 0; mt < 4; ++mt)
#pragma unroll
        for (int jt = 0; jt < 3; ++jt) {
            int nt = ng * 3 + jt;
            int wm = nt >> 3, nl = nt & 7;
            if (wm < 2) {
                unsigned short* C = (wm == 0) ? Cq : Ck;
#pragma unroll
                for (int rr = 0; rr < 4; ++rr)
                    C[(mt * 16 + quad * 4 + rr) * 136 + nl * 16 + l16] =
                        f2bf(acc[mt][jt][rr]);
            } else {
                i32x2 p;
                p[0] = cvtpk(acc[mt][jt][0], acc[mt][jt][1]);
                p[1] = cvtpk(acc[mt][jt][2], acc[mt][jt][3]);
                *(i32x2*)&Cv[(nl * 16 + l16) * 72 + mt * 16 + quad * 4] = p;
            }
        }
    __syncthreads();
    {
#pragma unroll
        for (int i = 0; i < 2; ++i) {
            int idx = i * 512 + t;
            int row = idx >> 4, seg = idx & 15;
            *(i32x4*)&qb[((size_t)(m0 + row)) * HD + seg * 8] = *(const i32x4*)&Cq[row * 136 + seg * 8];
            *(i32x4*)&kb[((size_t)(m0 + row)) * HD + seg * 8] = *(const i32x4*)&Ck[row * 136 + seg * 8];
        }
    }
    {
        const int b = m0 >> 12, s0 = m0 & 4095;
#pragma unroll
        for (int i = 0; i < 2; ++i) {
            int idx = i * 512 + t;
            int h = idx >> 3, seg = idx & 7;
            *(i32x4*)&vtb[(size_t)b * (HD * SEQ) + (size_t)h * SEQ + s0 + seg * 8] =
                *(const i32x4*)&Cv[h * 72 + seg * 8];
        }
    }
}

// ---------------- Flash attention: 4 waves x 32 q-rows (round-12 best — unchanged) ----------------
#define PADK 136
#define PADV 72
#define PADP 72
#define DEFER_THR 8.0f   // log2 domain: P bounded by 2^8=256, safe in bf16/f32

__global__ __launch_bounds__(256, 2) void flash_kernel(
    const unsigned short* __restrict__ qb, const unsigned short* __restrict__ kb,
    const unsigned short* __restrict__ vtb, unsigned short* __restrict__ Opart,
    float* __restrict__ mbuf, float* __restrict__ lbuf)
{
    __shared__ __align__(16) unsigned short Ks[64 * PADK];    // 17.4 KB
    __shared__ __align__(16) unsigned short Vt[128 * PADV];   // 18.4 KB
    __shared__ __align__(16) unsigned short Pt[128 * PADP];   // 18.4 KB

    const int bx   = blockIdx.x;
    const int slot = bx & 7, pp = bx >> 3;
    const int b    = slot >> 1;
    const int jj   = pp * 2 + (slot & 1);
    if (jj >= NJOBS) return;

    const int t    = threadIdx.x;
    const int lane = t & 63, w = t >> 6;     // 4 waves, 32 q-rows each
    const int quad = lane >> 4, l16 = lane & 15;

    int qi = 0, s = 0;
    for (qi = 0; qi < 32; ++qi) {
        int cnt = (qi + 5) / 5;
        if (jj < s + cnt) break;
        s += cnt;
    }
    const int c     = jj - s;
    const int qrow0 = qi * 128 + w * 32 + l16;        // sub 0
    const int qrow1 = qrow0 + 16;                     // sub 1
    const int jmax  = 2 * qi + 2;
    const int jbeg  = c * CHUNK;
    const int jend  = min(jbeg + CHUNK, jmax);
    const int wtop  = qi * 128 + w * 32;              // wave's lowest q-row (32-row span)

    bf16x8 qf0[4], qf1[4];
    {
        const unsigned short* qp0 = qb + ((size_t)b * SEQ + qrow0) * HD;
        const unsigned short* qp1 = qb + ((size_t)b * SEQ + qrow1) * HD;
#pragma unroll
        for (int ks = 0; ks < 4; ++ks) {
            qf0[ks] = *(const bf16x8*)&qp0[ks * 32 + quad * 8];
            qf1[ks] = *(const bf16x8*)&qp1[ks * 32 + quad * 8];
        }
    }

    f32x4 O0[8], O1[8];
#pragma unroll
    for (int i = 0; i < 8; ++i) {
        O0[i] = (f32x4){0.f, 0.f, 0.f, 0.f};
        O1[i] = (f32x4){0.f, 0.f, 0.f, 0.f};
    }
    float m0r = -1e30f, l0r = 0.f, m1r = -1e30f, l1r = 0.f;

    const unsigned short* kbb  = kb  + (size_t)b * SEQ * HD;
    const unsigned short* vtbb = vtb + (size_t)b * HD * SEQ;

    // staging: 256 threads cover 1024 16B chunks each of K and V^T
    i32x4 kr[4], vr[4];
#pragma unroll
    for (int i = 0; i < 4; ++i) {
        int gg = i * 256 + t;
        kr[i] = *(const i32x4*)&kbb[(size_t)jbeg * 64 * HD + (size_t)gg * 8];
        vr[i] = *(const i32x4*)&vtbb[(size_t)(gg >> 3) * SEQ + jbeg * 64 + (gg & 7) * 8];
    }

    for (int j0 = jbeg; j0 < jend; ++j0) {
        __syncthreads();   // prior iteration's reads of Ks/Vt complete (WAR)
#pragma unroll
        for (int i = 0; i < 4; ++i) {
            int gg = i * 256 + t;
            *(i32x4*)&Ks[(gg >> 4) * PADK + (gg & 15) * 8] = kr[i];
            *(i32x4*)&Vt[(gg >> 3) * PADV + (gg & 7) * 8] = vr[i];
        }
        __syncthreads();

        // issue next tile's loads NOW — latency hides under this tile's compute
        if (j0 + 1 < jend) {
            const int j1 = j0 + 1;
#pragma unroll
            for (int i = 0; i < 4; ++i) {
                int gg = i * 256 + t;
                kr[i] = *(const i32x4*)&kbb[(size_t)j1 * 64 * HD + (size_t)gg * 8];
                vr[i] = *(const i32x4*)&vtbb[(size_t)(gg >> 3) * SEQ + j1 * 64 + (gg & 7) * 8];
            }
        }

        // fully-masked tile for this wave's 32 rows? -> skip compute
        if (j0 * 64 > wtop + 31) continue;

        // ---- S^T = K . Q^T : each kf read feeds BOTH q-subtiles ----
        f32x4 st0[4], st1[4];
#pragma unroll
        for (int mt = 0; mt < 4; ++mt) {
            st0[mt] = (f32x4){0.f, 0.f, 0.f, 0.f};
            st1[mt] = (f32x4){0.f, 0.f, 0.f, 0.f};
        }
        __builtin_amdgcn_s_setprio(1);
#pragma unroll
        for (int mt = 0; mt < 4; ++mt)
#pragma unroll
            for (int ks = 0; ks < 4; ++ks) {
                bf16x8 kf = *(const bf16x8*)&Ks[(mt * 16 + l16) * PADK + ks * 32 + quad * 8];
                st0[mt] = __builtin_amdgcn_mfma_f32_16x16x32_bf16(kf, qf0[ks], st0[mt], 0, 0, 0);
                st1[mt] = __builtin_amdgcn_mfma_f32_16x16x32_bf16(kf, qf1[ks], st1[mt], 0, 0, 0);
            }
        __builtin_amdgcn_s_setprio(0);

        // ---- causal mask (both subtiles) ----
        if (j0 * 64 + 63 > wtop) {
#pragma unroll
            for (int mt = 0; mt < 4; ++mt)
#pragma unroll
                for (int rr = 0; rr < 4; ++rr) {
                    int kv = j0 * 64 + mt * 16 + quad * 4 + rr;
                    if (kv > qrow0) st0[mt][rr] = -1e30f;
                    if (kv > qrow1) st1[mt][rr] = -1e30f;
                }
        }

        // ---- online softmax, exp2 domain, per subtile (lane owns one q-row each) ----
        {
            float mx = -1e30f;
#pragma unroll
            for (int mt = 0; mt < 4; ++mt)
#pragma unroll
                for (int rr = 0; rr < 4; ++rr) mx = fmaxf(mx, st0[mt][rr]);
            mx = fmaxf(mx, __shfl_xor(mx, 16));
            mx = fmaxf(mx, __shfl_xor(mx, 32));
            if (!__all(mx <= m0r + DEFER_THR)) {
                const float m_new = fmaxf(m0r, mx);
                const float alpha = exp2f(m0r - m_new);
                l0r *= alpha;
#pragma unroll
                for (int i = 0; i < 8; ++i) {
                    O0[i][0] *= alpha; O0[i][1] *= alpha; O0[i][2] *= alpha; O0[i][3] *= alpha;
                }
                m0r = m_new;
            }
            float psum = 0.f;
#pragma unroll
            for (int mt = 0; mt < 4; ++mt)
#pragma unroll
                for (int rr = 0; rr < 4; ++rr) {
                    float p = exp2f(st0[mt][rr] - m0r);
                    st0[mt][rr] = p;
                    psum += p;
                }
            psum += __shfl_xor(psum, 16);
            psum += __shfl_xor(psum, 32);
            l0r += psum;
            // pack sub0 P to LDS immediately so st0 dies here (register pressure)
#pragma unroll
            for (int mt = 0; mt < 4; ++mt) {
                i32x2 p;
                p[0] = cvtpk(st0[mt][0], st0[mt][1]);
                p[1] = cvtpk(st0[mt][2], st0[mt][3]);
                *(i32x2*)&Pt[(w * 32 + l16) * PADP + mt * 16 + quad * 4] = p;
            }
        }
        {
            float mx = -1e30f;
#pragma unroll
            for (int mt = 0; mt < 4; ++mt)
#pragma unroll
                for (int rr = 0; rr < 4; ++rr) mx = fmaxf(mx, st1[mt][rr]);
            mx = fmaxf(mx, __shfl_xor(mx, 16));
            mx = fmaxf(mx, __shfl_xor(mx, 32));
            if (!__all(mx <= m1r + DEFER_THR)) {
                const float m_new = fmaxf(m1r, mx);
                const float alpha = exp2f(m1r - m_new);
                l1r *= alpha;
#pragma unroll
                for (int i = 0; i < 8; ++i) {
                    O1[i][0] *= alpha; O1[i][1] *= alpha; O1[i][2] *= alpha; O1[i][3] *= alpha;
                }
                m1r = m_new;
            }
            float psum = 0.f;
#pragma unroll
            for (int mt = 0; mt < 4; ++mt)
#pragma unroll
                for (int rr = 0; rr < 4; ++rr) {
                    float p = exp2f(st1[mt][rr] - m1r);
                    st1[mt][rr] = p;
                    psum += p;
                }
            psum += __shfl_xor(psum, 16);
            psum += __shfl_xor(psum, 32);
            l1r += psum;
#pragma unroll
            for (int mt = 0; mt < 4; ++mt) {
                i32x2 p;
                p[0] = cvtpk(st1[mt][0], st1[mt][1]);
                p[1] = cvtpk(st1[mt][2], st1[mt][3]);
                *(i32x2*)&Pt[(w * 32 + 16 + l16) * PADP + mt * 16 + quad * 4] = p;
            }
        }

        // ---- O^T += V^T . P^T : each vf read feeds BOTH q-subtiles ----
        bf16x8 pf00 = *(const bf16x8*)&Pt[(w * 32 + l16) * PADP + quad * 8];
        bf16x8 pf01 = *(const bf16x8*)&Pt[(w * 32 + l16) * PADP + 32 + quad * 8];
        bf16x8 pf10 = *(const bf16x8*)&Pt[(w * 32 + 16 + l16) * PADP + quad * 8];
        bf16x8 pf11 = *(const bf16x8*)&Pt[(w * 32 + 16 + l16) * PADP + 32 + quad * 8];
        __builtin_amdgcn_s_setprio(1);
#pragma unroll
        for (int mt = 0; mt < 8; ++mt) {
            bf16x8 vf0 = *(const bf16x8*)&Vt[(mt * 16 + l16) * PADV + quad * 8];
            bf16x8 vf1 = *(const bf16x8*)&Vt[(mt * 16 + l16) * PADV + 32 + quad * 8];
            O0[mt] = __builtin_amdgcn_mfma_f32_16x16x32_bf16(vf0, pf00, O0[mt], 0, 0, 0);
            O0[mt] = __builtin_amdgcn_mfma_f32_16x16x32_bf16(vf1, pf01, O0[mt], 0, 0, 0);
            O1[mt] = __builtin_amdgcn_mfma_f32_16x16x32_bf16(vf0, pf10, O1[mt], 0, 0, 0);
            O1[mt] = __builtin_amdgcn_mfma_f32_16x16x32_bf16(vf1, pf11, O1[mt], 0, 0, 0);
        }
        __builtin_amdgcn_s_setprio(0);
    }

    // ---- partial epilogue: unnormalized O (bf16, cvt_pk) + m,l (log2 domain) ----
    const size_t jobbase = (size_t)b * NJOBS + jj;
    {
        const int r = w * 32 + l16;
        unsigned short* po = Opart + jobbase * (128 * 128) + (size_t)r * 128;
#pragma unroll
        for (int mt = 0; mt < 8; ++mt) {
            i32x2 p;
            p[0] = cvtpk(O0[mt][0], O0[mt][1]);
            p[1] = cvtpk(O0[mt][2], O0[mt][3]);
            *(i32x2*)&po[mt * 16 + quad * 4] = p;
        }
        if (quad == 0) {
            mbuf[jobbase * 128 + r] = m0r;
            lbuf[jobbase * 128 + r] = l0r;
        }
    }
    {
        const int r = w * 32 + 16 + l16;
        unsigned short* po = Opart + jobbase * (128 * 128) + (size_t)r * 128;
#pragma unroll
        for (int mt = 0; mt < 8; ++mt) {
            i32x2 p;
            p[0] = cvtpk(O1[mt][0], O1[mt][1]);
            p[1] = cvtpk(O1[mt][2], O1[mt][3]);
            *(i32x2*)&po[mt * 16 + quad * 4] = p;
        }
        if (quad == 0) {
            mbuf[jobbase * 128 + r] = m1r;
            lbuf[jobbase * 128 + r] = l1r;
        }
    }
}

// ---------------- Combine partials (round-13 4-way z-split — verified) ----------------
// grid (32, 4, 4) x 512 thr: block z covers 32 rows; thread -> row = bz*32 + (t>>4),
// 8 head cols at (t&15)*8. One 16B load per chunk.
__global__ __launch_bounds__(512) void combine_kernel(
    const unsigned short* __restrict__ Opart, const float* __restrict__ mbuf,
    const float* __restrict__ lbuf, float* __restrict__ out)
{
    const int qi = blockIdx.x, b = blockIdx.y;
    const int nc = (qi + 5) / 5;
    int j0 = 0;
    for (int q = 0; q < qi; ++q) j0 += (q + 5) / 5;
    const int t = threadIdx.x;
    const int row = blockIdx.z * 32 + (t >> 4);
    const int cg  = (t & 15) * 8;

    float mv[MAXC], lv[MAXC];
    float M = -1e30f;
#pragma unroll
    for (int c2 = 0; c2 < MAXC; ++c2) {
        if (c2 < nc) {
            const size_t jb = (size_t)b * NJOBS + j0 + c2;
            mv[c2] = mbuf[jb * 128 + row];
            lv[c2] = lbuf[jb * 128 + row];
            M = fmaxf(M, mv[c2]);
        } else { mv[c2] = -1e30f; lv[c2] = 0.f; }
    }
    float L = 0.f;
#pragma unroll
    for (int c2 = 0; c2 < MAXC; ++c2)
        if (c2 < nc) L += exp2f(mv[c2] - M) * lv[c2];
    const float Linv = 1.0f / L;

    float acc[8];
#pragma unroll
    for (int i = 0; i < 8; ++i) acc[i] = 0.f;
#pragma unroll
    for (int c2 = 0; c2 < MAXC; ++c2) {
        if (c2 < nc) {
            const float wgt = exp2f(mv[c2] - M) * Linv;
            const unsigned short* po = Opart + ((size_t)b * NJOBS + j0 + c2) * (128 * 128) +
                                       (size_t)row * 128 + cg;
            i32x4 d = *(const i32x4*)&po[0];
#pragma unroll
            for (int e = 0; e < 4; ++e) {
                unsigned int u = (unsigned int)d[e];
                acc[e * 2]     = fmaf(wgt, bf2f((unsigned short)(u & 0xffff)), acc[e * 2]);
                acc[e * 2 + 1] = fmaf(wgt, bf2f((unsigned short)(u >> 16)),   acc[e * 2 + 1]);
            }
        }
    }
    float* op = out + ((size_t)b * SEQ + qi * 128 + row) * HD + cg;
#pragma unroll
    for (int i = 0; i < 2; ++i) {
        float4 res;
        res.x = acc[i * 4]; res.y = acc[i * 4 + 1];
        res.z = acc[i * 4 + 2]; res.w = acc[i * 4 + 3];
        *(float4*)&op[i * 4] = res;
    }
}

extern "C" void kernel_launch(void* const* d_in, const int* in_sizes, int n_in,
                              void* d_out, int out_size, void* d_ws, size_t ws_size,
                              hipStream_t stream) {
    const float* x  = (const float*)d_in[0];
    const float* Wq = (const float*)d_in[1];
    const float* Wk = (const float*)d_in[2];
    const float* Wv = (const float*)d_in[3];

    unsigned short* qb    = (unsigned short*)d_ws;          // [16384][128] bf16
    unsigned short* kb    = qb  + (size_t)MROWS * HD;       // [16384][128] bf16
    unsigned short* vtb   = kb  + (size_t)MROWS * HD;       // [4][128][4096] bf16
    unsigned short* Wt    = vtb + (size_t)MROWS * HD;       // [24][32][64][8] bf16 frag-order
    unsigned short* Opart = Wt  + (size_t)3 * HD * EMB;     // [4][119][128][128] bf16
    float* mbuf = (float*)(Opart + (size_t)BATCH * NJOBS * 128 * 128);
    float* lbuf = mbuf + (size_t)BATCH * NJOBS * 128;
    float* out = (float*)d_out;

    wtrans_kernel <<<dim3(64, 3),    dim3(256), 0, stream>>>(Wq, Wk, Wv, Wt);
    qkv_kernel    <<<dim3(256),      dim3(512), 0, stream>>>(x, Wt, qb, kb, vtb);
    flash_kernel  <<<dim3(480),      dim3(256), 0, stream>>>(qb, kb, vtb, Opart, mbuf, lbuf);
    combine_kernel<<<dim3(32, 4, 4), dim3(512), 0, stream>>>(Opart, mbuf, lbuf, out);
}